// Round 1
// baseline (1090.013 us; speedup 1.0000x reference)
//
#include <hip/hip_runtime.h>
#include <cstdint>
#include <cstddef>

#define B_    16
#define T_    1024
#define NF_   64
#define D_    128
#define H_    4
#define DFF_  512
#define M_    16384   // B_*T_

#define OUT_SP     0
#define OUT_REG    65536
#define OUT_PROBS  81920
#define OUT_H      147456
#define OUT_FS     2244608

typedef float f32x4 __attribute__((ext_vector_type(4)));
typedef short bf16x8 __attribute__((ext_vector_type(8)));
typedef unsigned short u16;
typedef unsigned int u32;

__device__ __forceinline__ u16 f2b(float v) {
  union { float f; u32 u; } x; x.f = v;
  u32 r = x.u + 0x7fffu + ((x.u >> 16) & 1u);   // RNE to bf16
  return (u16)(r >> 16);
}
__device__ __forceinline__ float b2f(u16 b) {
  union { u32 u; float f; } x; x.u = ((u32)b) << 16; return x.f;
}
__device__ __forceinline__ void gload16(const void* g, void* l) {
  __builtin_amdgcn_global_load_lds((const __attribute__((address_space(1))) void*)g,
                                   (__attribute__((address_space(3))) void*)l, 16, 0, 0);
}
__device__ __forceinline__ f32x4 mfma_bf16(bf16x8 a, bf16x8 b, f32x4 c) {
  return __builtin_amdgcn_mfma_f32_16x16x32_bf16(a, b, c, 0, 0, 0);
}

// ---------------- split fp32 -> (hi, lo) bf16 planes ----------------
__global__ void k_split(const float* __restrict__ s, u16* __restrict__ hi,
                        u16* __restrict__ lo, int n) {
  int i = blockIdx.x * blockDim.x + threadIdx.x;
  if (i >= n) return;
  float v = s[i];
  u16 h = f2b(v);
  hi[i] = h;
  lo[i] = f2b(v - b2f(h));
}

// ---------------- normalized centroids ----------------
__global__ void k_cnorm(const float* __restrict__ c, float* __restrict__ cn) {
  const int lane = threadIdx.x;  // 64
  for (int r = 0; r < 4; ++r) {
    float2 v = *(const float2*)&c[r * 128 + lane * 2];
    float ss = v.x * v.x + v.y * v.y;
#pragma unroll
    for (int d = 1; d < 64; d <<= 1) ss += __shfl_xor(ss, d, 64);
    float nrm = fmaxf(sqrtf(ss), 1e-12f);
    float2 o; o.x = v.x / nrm; o.y = v.y / nrm;
    *(float2*)&cn[r * 128 + lane * 2] = o;
  }
}

// ---------------- split-bf16 GEMM: C[M,N] = A[M,K] @ W[N,K]^T + bias ----------------
// OUTMODE bit0: write fp32 C, bit1: write (hi,lo) planes. RELU optional.
template <int RELU, int OUTMODE>
__global__ __launch_bounds__(256)
void k_gemm(const u16* __restrict__ Ahi, const u16* __restrict__ Alo,
            const u16* __restrict__ Whi, const u16* __restrict__ Wlo,
            const float* __restrict__ bias,
            float* __restrict__ Cf, u16* __restrict__ Chi, u16* __restrict__ Clo,
            int N, int K) {
  __shared__ u16 lA[2][128 * 32];
  __shared__ u16 lB[2][64 * 32];
  const int tid = threadIdx.x;
  const int wv = tid >> 6, lane = tid & 63;
  const int lo16 = lane & 15, hi2 = lane >> 4;
  const int m0 = blockIdx.x * 128, n0 = blockIdx.y * 64;
  const int ar = tid >> 2, ac = (tid & 3) * 8;

  f32x4 acc[2][4];
#pragma unroll
  for (int i = 0; i < 2; ++i)
#pragma unroll
    for (int j = 0; j < 4; ++j) acc[i][j] = (f32x4){0.f, 0.f, 0.f, 0.f};

  for (int k0 = 0; k0 < K; k0 += 32) {
    __syncthreads();
    gload16(Ahi + (size_t)(m0 + ar) * K + k0 + ac,      &lA[0][ar * 32 + ac]);
    gload16(Ahi + (size_t)(m0 + 64 + ar) * K + k0 + ac, &lA[0][(64 + ar) * 32 + ac]);
    gload16(Alo + (size_t)(m0 + ar) * K + k0 + ac,      &lA[1][ar * 32 + ac]);
    gload16(Alo + (size_t)(m0 + 64 + ar) * K + k0 + ac, &lA[1][(64 + ar) * 32 + ac]);
    gload16(Whi + (size_t)(n0 + ar) * K + k0 + ac,      &lB[0][ar * 32 + ac]);
    gload16(Wlo + (size_t)(n0 + ar) * K + k0 + ac,      &lB[1][ar * 32 + ac]);
    __syncthreads();

    bf16x8 af[2][2], bf[4][2];
#pragma unroll
    for (int rt = 0; rt < 2; ++rt)
#pragma unroll
      for (int p = 0; p < 2; ++p)
        af[rt][p] = *(const bf16x8*)&lA[p][(wv * 32 + rt * 16 + lo16) * 32 + hi2 * 8];
#pragma unroll
    for (int ct = 0; ct < 4; ++ct)
#pragma unroll
      for (int p = 0; p < 2; ++p)
        bf[ct][p] = *(const bf16x8*)&lB[p][(ct * 16 + lo16) * 32 + hi2 * 8];
#pragma unroll
    for (int rt = 0; rt < 2; ++rt)
#pragma unroll
      for (int ct = 0; ct < 4; ++ct) {
        acc[rt][ct] = mfma_bf16(af[rt][0], bf[ct][0], acc[rt][ct]);
        acc[rt][ct] = mfma_bf16(af[rt][0], bf[ct][1], acc[rt][ct]);
        acc[rt][ct] = mfma_bf16(af[rt][1], bf[ct][0], acc[rt][ct]);
      }
  }

#pragma unroll
  for (int rt = 0; rt < 2; ++rt)
#pragma unroll
    for (int ct = 0; ct < 4; ++ct) {
      const int col = n0 + ct * 16 + lo16;
      const float bc = bias[col];
#pragma unroll
      for (int r = 0; r < 4; ++r) {
        const int row = m0 + wv * 32 + rt * 16 + hi2 * 4 + r;
        float v = acc[rt][ct][r] + bc;
        if (RELU) v = fmaxf(v, 0.f);
        const size_t idx = (size_t)row * N + col;
        if (OUTMODE & 1) Cf[idx] = v;
        if (OUTMODE & 2) {
          u16 hb = f2b(v);
          Chi[idx] = hb;
          Clo[idx] = f2b(v - b2f(hb));
        }
      }
    }
}

// ---------------- V transpose prep: Vt[b,h,d,t] from qkv[b,t,256+h*32+d] ----------------
__global__ void k_vtprep(const u16* __restrict__ qh, const u16* __restrict__ ql,
                         u16* __restrict__ vh, u16* __restrict__ vl) {
  int i = blockIdx.x * 256 + threadIdx.x;  // 0..2M-1
  int t = i & 1023;
  int d = (i >> 10) & 31;
  int bh = i >> 15;
  int b = bh >> 2, hh = bh & 3;
  size_t src = ((size_t)(b * 1024 + t)) * 384 + 256 + hh * 32 + d;
  size_t dst = ((size_t)(bh * 32 + d)) * 1024 + t;
  vh[dst] = qh[src];
  vl[dst] = ql[src];
}

// ---------------- flash attention, split-bf16 MFMA ----------------
__global__ __launch_bounds__(256)
void k_attn(const u16* __restrict__ qkh, const u16* __restrict__ qkl,
            const u16* __restrict__ vth, const u16* __restrict__ vtl,
            u16* __restrict__ ohi, u16* __restrict__ olo) {
  __shared__ u16 lQ[2][64 * 32];
  __shared__ u16 lK[2][64 * 32];
  __shared__ u16 lV[2][32 * 64];
  __shared__ float lP[4][16 * 64];

  const int tid = threadIdx.x;
  const int wv = tid >> 6, lane = tid & 63;
  const int lo16 = lane & 15, hi2 = lane >> 4;
  const int qt = blockIdx.x;   // 0..15
  const int bh = blockIdx.y;   // 0..63
  const int b = bh >> 2, h = bh & 3;
  const int ar = tid >> 2, ac = (tid & 3) * 8;

  const size_t qrow0 = (size_t)b * T_ + qt * 64;
  gload16(qkh + (qrow0 + ar) * 384 + h * 32 + ac, &lQ[0][ar * 32 + ac]);
  gload16(qkl + (qrow0 + ar) * 384 + h * 32 + ac, &lQ[1][ar * 32 + ac]);
  __syncthreads();
  bf16x8 qf0 = *(const bf16x8*)&lQ[0][(wv * 16 + lo16) * 32 + hi2 * 8];
  bf16x8 qf1 = *(const bf16x8*)&lQ[1][(wv * 16 + lo16) * 32 + hi2 * 8];

  f32x4 oacc[2];
  oacc[0] = (f32x4){0.f, 0.f, 0.f, 0.f};
  oacc[1] = (f32x4){0.f, 0.f, 0.f, 0.f};
  float mrow[4] = {-1e30f, -1e30f, -1e30f, -1e30f};
  float lrow[4] = {0.f, 0.f, 0.f, 0.f};
  const float scale = 0.17677669529663687f;  // 1/sqrt(32)

  for (int kt = 0; kt < 16; ++kt) {
    __syncthreads();
    const size_t krow0 = (size_t)b * T_ + kt * 64;
    gload16(qkh + (krow0 + ar) * 384 + 128 + h * 32 + ac, &lK[0][ar * 32 + ac]);
    gload16(qkl + (krow0 + ar) * 384 + 128 + h * 32 + ac, &lK[1][ar * 32 + ac]);
    const size_t vrow = ((size_t)bh * 32 + (tid >> 3)) * T_ + kt * 64 + (tid & 7) * 8;
    gload16(vth + vrow, &lV[0][(tid >> 3) * 64 + (tid & 7) * 8]);
    gload16(vtl + vrow, &lV[1][(tid >> 3) * 64 + (tid & 7) * 8]);
    __syncthreads();

    f32x4 s[4];
#pragma unroll
    for (int ct = 0; ct < 4; ++ct) {
      bf16x8 kf0 = *(const bf16x8*)&lK[0][(ct * 16 + lo16) * 32 + hi2 * 8];
      bf16x8 kf1 = *(const bf16x8*)&lK[1][(ct * 16 + lo16) * 32 + hi2 * 8];
      f32x4 z = (f32x4){0.f, 0.f, 0.f, 0.f};
      z = mfma_bf16(qf0, kf0, z);
      z = mfma_bf16(qf0, kf1, z);
      z = mfma_bf16(qf1, kf0, z);
      s[ct] = z;
    }
#pragma unroll
    for (int r = 0; r < 4; ++r) {
      float v0 = s[0][r] * scale, v1 = s[1][r] * scale;
      float v2 = s[2][r] * scale, v3 = s[3][r] * scale;
      float mx = fmaxf(fmaxf(v0, v1), fmaxf(v2, v3));
#pragma unroll
      for (int d2 = 1; d2 < 16; d2 <<= 1) mx = fmaxf(mx, __shfl_xor(mx, d2, 64));
      float mnew = fmaxf(mrow[r], mx);
      float corr = __expf(mrow[r] - mnew);
      mrow[r] = mnew;
      float p0 = __expf(v0 - mnew), p1 = __expf(v1 - mnew);
      float p2 = __expf(v2 - mnew), p3 = __expf(v3 - mnew);
      float rs = p0 + p1 + p2 + p3;
#pragma unroll
      for (int d2 = 1; d2 < 16; d2 <<= 1) rs += __shfl_xor(rs, d2, 64);
      lrow[r] = lrow[r] * corr + rs;
      oacc[0][r] *= corr;
      oacc[1][r] *= corr;
      const int prow = hi2 * 4 + r;
      lP[wv][prow * 64 + 0 * 16 + lo16] = p0;
      lP[wv][prow * 64 + 1 * 16 + lo16] = p1;
      lP[wv][prow * 64 + 2 * 16 + lo16] = p2;
      lP[wv][prow * 64 + 3 * 16 + lo16] = p3;
    }
    // intra-wave LDS write->read hazard: drain DS queue before cross-lane read
    asm volatile("s_waitcnt lgkmcnt(0)" ::: "memory");
#pragma unroll
    for (int c = 0; c < 2; ++c) {
      const float* pp = &lP[wv][lo16 * 64 + c * 32 + hi2 * 8];
      float4 pa = *(const float4*)pp;
      float4 pb = *(const float4*)(pp + 4);
      float pv[8] = {pa.x, pa.y, pa.z, pa.w, pb.x, pb.y, pb.z, pb.w};
      bf16x8 ph, pl;
#pragma unroll
      for (int j = 0; j < 8; ++j) {
        u16 hb = f2b(pv[j]);
        ph[j] = (short)hb;
        pl[j] = (short)f2b(pv[j] - b2f(hb));
      }
#pragma unroll
      for (int ct2 = 0; ct2 < 2; ++ct2) {
        bf16x8 vf0 = *(const bf16x8*)&lV[0][(ct2 * 16 + lo16) * 64 + c * 32 + hi2 * 8];
        bf16x8 vf1 = *(const bf16x8*)&lV[1][(ct2 * 16 + lo16) * 64 + c * 32 + hi2 * 8];
        oacc[ct2] = mfma_bf16(ph, vf0, oacc[ct2]);
        oacc[ct2] = mfma_bf16(ph, vf1, oacc[ct2]);
        oacc[ct2] = mfma_bf16(pl, vf0, oacc[ct2]);
      }
    }
  }
#pragma unroll
  for (int ct2 = 0; ct2 < 2; ++ct2)
#pragma unroll
    for (int r = 0; r < 4; ++r) {
      float v = oacc[ct2][r] / lrow[r];
      const int t = qt * 64 + wv * 16 + hi2 * 4 + r;
      const size_t idx = ((size_t)b * T_ + t) * D_ + h * 32 + ct2 * 16 + lo16;
      u16 hb = f2b(v);
      ohi[idx] = hb;
      olo[idx] = f2b(v - b2f(hb));
    }
}

// ---------------- fused residual add + LayerNorm ----------------
__global__ __launch_bounds__(256)
void k_lnadd(const float* hin, const float* __restrict__ add,
             const float* __restrict__ w, const float* __restrict__ b,
             float* hout, u16* __restrict__ hhi, u16* __restrict__ hlo) {
  const int row = blockIdx.x * 4 + (threadIdx.x >> 6);
  const int lane = threadIdx.x & 63;
  const size_t base = (size_t)row * D_ + lane * 2;
  float2 x = *(const float2*)(hin + base);
  float2 a = *(const float2*)(add + base);
  x.x += a.x; x.y += a.y;
  float s = x.x + x.y;
#pragma unroll
  for (int d2 = 1; d2 < 64; d2 <<= 1) s += __shfl_xor(s, d2, 64);
  const float m = s * (1.f / 128.f);
  float dx = x.x - m, dy = x.y - m;
  float q = dx * dx + dy * dy;
#pragma unroll
  for (int d2 = 1; d2 < 64; d2 <<= 1) q += __shfl_xor(q, d2, 64);
  const float inv = rsqrtf(q * (1.f / 128.f) + 1e-5f);
  const float2 ww = *(const float2*)(w + lane * 2);
  const float2 bb = *(const float2*)(b + lane * 2);
  float y0 = dx * inv * ww.x + bb.x;
  float y1 = dy * inv * ww.y + bb.y;
  float2 yo; yo.x = y0; yo.y = y1;
  *(float2*)(hout + base) = yo;
  u16 h0 = f2b(y0), h1 = f2b(y1);
  u16 l0 = f2b(y0 - b2f(h0)), l1 = f2b(y1 - b2f(h1));
  *(u32*)(hhi + base) = (u32)h0 | ((u32)h1 << 16);
  *(u32*)(hlo + base) = (u32)l0 | ((u32)l1 << 16);
}

// ---------------- head: final LN -> h out, cosine logits -> probs out ----------------
__global__ __launch_bounds__(256)
void k_head(const float* __restrict__ hin, const float* __restrict__ w,
            const float* __restrict__ bws, const float* __restrict__ cn,
            const float* __restrict__ temp, float* __restrict__ out) {
  const int row = blockIdx.x * 4 + (threadIdx.x >> 6);
  const int lane = threadIdx.x & 63;
  const size_t base = (size_t)row * D_ + lane * 2;
  float2 x = *(const float2*)(hin + base);
  float s = x.x + x.y;
#pragma unroll
  for (int d2 = 1; d2 < 64; d2 <<= 1) s += __shfl_xor(s, d2, 64);
  float m = s * (1.f / 128.f);
  float dx = x.x - m, dy = x.y - m;
  float q = dx * dx + dy * dy;
#pragma unroll
  for (int d2 = 1; d2 < 64; d2 <<= 1) q += __shfl_xor(q, d2, 64);
  float inv = rsqrtf(q * (1.f / 128.f) + 1e-5f);
  float2 ww = *(const float2*)(w + lane * 2);
  float2 bb = *(const float2*)(bws + lane * 2);
  float y0 = dx * inv * ww.x + bb.x;
  float y1 = dy * inv * ww.y + bb.y;
  float2 yo; yo.x = y0; yo.y = y1;
  *(float2*)(out + OUT_H + base) = yo;
  float ss = y0 * y0 + y1 * y1;
#pragma unroll
  for (int d2 = 1; d2 < 64; d2 <<= 1) ss += __shfl_xor(ss, d2, 64);
  float nrm = fmaxf(sqrtf(ss), 1e-12f);
  float z0 = y0 / nrm, z1 = y1 / nrm;
  float lg[4];
#pragma unroll
  for (int rr = 0; rr < 4; ++rr)
    lg[rr] = z0 * cn[rr * 128 + lane * 2] + z1 * cn[rr * 128 + lane * 2 + 1];
#pragma unroll
  for (int d2 = 1; d2 < 64; d2 <<= 1) {
#pragma unroll
    for (int rr = 0; rr < 4; ++rr) lg[rr] += __shfl_xor(lg[rr], d2, 64);
  }
  float ts = 1.f / fmaxf(temp[0], 1e-4f);
#pragma unroll
  for (int rr = 0; rr < 4; ++rr) lg[rr] *= ts;
  float mx = fmaxf(fmaxf(lg[0], lg[1]), fmaxf(lg[2], lg[3]));
  float e0 = __expf(lg[0] - mx), e1 = __expf(lg[1] - mx);
  float e2 = __expf(lg[2] - mx), e3 = __expf(lg[3] - mx);
  float es = e0 + e1 + e2 + e3;
  float pr = ((lane == 0) ? e0 : (lane == 1) ? e1 : (lane == 2) ? e2 : e3) / es;
  if (lane < 4) out[OUT_PROBS + (size_t)row * 4 + lane] = pr;
}

// ---------------- sequential GRU smoothing scan (single wave) ----------------
__global__ __launch_bounds__(64)
void k_gru(const float* __restrict__ probs, const float* __restrict__ init,
           const float* __restrict__ wih, const float* __restrict__ whh,
           const float* __restrict__ bih, const float* __restrict__ bhh,
           float* __restrict__ out) {
  __shared__ float pbuf[64][64];
  __shared__ float sbuf[64][64];
  __shared__ float abuf[64][16];
  const int tid = threadIdx.x;
  const int b = tid >> 2, r = tid & 3;
  float Wi[3][4], Wh[3][4], Bi[3], Bh[3];
#pragma unroll
  for (int g = 0; g < 3; ++g) {
    Bi[g] = bih[g * 4 + r];
    Bh[g] = bhh[g * 4 + r];
#pragma unroll
    for (int j = 0; j < 4; ++j) {
      Wi[g][j] = wih[(g * 4 + r) * 4 + j];
      Wh[g][j] = whh[(g * 4 + r) * 4 + j];
    }
  }
  float st = init[tid];
  for (int c = 0; c < 16; ++c) {
    for (int k = tid; k < 4096; k += 64) {
      int bb = k >> 8, rem = k & 255;
      pbuf[rem >> 2][(bb << 2) + (rem & 3)] =
          probs[((size_t)(bb * 1024 + c * 64 + (rem >> 2)) << 2) + (rem & 3)];
    }
    __syncthreads();
    for (int s2 = 0; s2 < 64; ++s2) {
      float4 p = *(const float4*)&pbuf[s2][b * 4];
      float gi0 = Bi[0] + Wi[0][0]*p.x + Wi[0][1]*p.y + Wi[0][2]*p.z + Wi[0][3]*p.w;
      float gi1 = Bi[1] + Wi[1][0]*p.x + Wi[1][1]*p.y + Wi[1][2]*p.z + Wi[1][3]*p.w;
      float gi2 = Bi[2] + Wi[2][0]*p.x + Wi[2][1]*p.y + Wi[2][2]*p.z + Wi[2][3]*p.w;
      int base = tid & ~3;
      float s0 = __shfl(st, base + 0, 64);
      float s1 = __shfl(st, base + 1, 64);
      float s2v = __shfl(st, base + 2, 64);
      float s3 = __shfl(st, base + 3, 64);
      float gh0 = Bh[0] + Wh[0][0]*s0 + Wh[0][1]*s1 + Wh[0][2]*s2v + Wh[0][3]*s3;
      float gh1 = Bh[1] + Wh[1][0]*s0 + Wh[1][1]*s1 + Wh[1][2]*s2v + Wh[1][3]*s3;
      float gh2 = Bh[2] + Wh[2][0]*s0 + Wh[2][1]*s1 + Wh[2][2]*s2v + Wh[2][3]*s3;
      float rg = 1.f / (1.f + __expf(-(gi0 + gh0)));
      float zg = 1.f / (1.f + __expf(-(gi1 + gh1)));
      float nx = gi2 + rg * gh2;
      float e2 = __expf(2.f * nx);
      float ng = 1.f - 2.f / (e2 + 1.f);   // tanh, overflow-safe
      float sn = (1.f - zg) * ng + zg * st;
      float myp = (r == 0) ? p.x : (r == 1) ? p.y : (r == 2) ? p.z : p.w;
      sn = sn * 0.9f + myp * 0.1f;
      st = sn;
      sbuf[s2][tid] = sn;
      float v0 = __shfl(sn, base + 0, 64);
      float v1 = __shfl(sn, base + 1, 64);
      float v2 = __shfl(sn, base + 2, 64);
      float v3 = __shfl(sn, base + 3, 64);
      if (r == 0) {
        int am = 0; float bv = v0;
        if (v1 > bv) { bv = v1; am = 1; }
        if (v2 > bv) { bv = v2; am = 2; }
        if (v3 > bv) { bv = v3; am = 3; }
        abuf[s2][b] = (float)am;
      }
    }
    __syncthreads();
    for (int k = tid; k < 4096; k += 64) {
      int bb = k >> 8, rem = k & 255;
      out[OUT_SP + ((size_t)(bb * 1024 + c * 64 + (rem >> 2)) << 2) + (rem & 3)] =
          sbuf[rem >> 2][(bb << 2) + (rem & 3)];
    }
    for (int k = tid; k < 1024; k += 64) {
      int bb = k >> 6, tt = k & 63;
      out[OUT_REG + bb * 1024 + c * 64 + tt] = abuf[tt][bb];
    }
  }
  out[OUT_FS + tid] = st;
}

// ---------------- launch ----------------
extern "C" void kernel_launch(void* const* d_in, const int* in_sizes, int n_in,
                              void* d_out, int out_size, void* d_ws, size_t ws_size,
                              hipStream_t stream) {
  (void)in_sizes; (void)n_in; (void)out_size; (void)ws_size;
  const float* x     = (const float*)d_in[0];
  const float* init  = (const float*)d_in[1];
  const float* in_w  = (const float*)d_in[2];
  const float* in_b  = (const float*)d_in[3];
  const float* qkv_w = (const float*)d_in[4];
  const float* qkv_b = (const float*)d_in[5];
  const float* out_w = (const float*)d_in[6];
  const float* out_b = (const float*)d_in[7];
  const float* ln1w  = (const float*)d_in[8];
  const float* ln1b  = (const float*)d_in[9];
  const float* ff1w  = (const float*)d_in[10];
  const float* ff1b  = (const float*)d_in[11];
  const float* ff2w  = (const float*)d_in[12];
  const float* ff2b  = (const float*)d_in[13];
  const float* ln2w  = (const float*)d_in[14];
  const float* ln2b  = (const float*)d_in[15];
  const float* nw    = (const float*)d_in[16];
  const float* nb    = (const float*)d_in[17];
  const float* cent  = (const float*)d_in[18];
  const float* temp  = (const float*)d_in[19];
  const float* gwih  = (const float*)d_in[20];
  const float* gwhh  = (const float*)d_in[21];
  const float* gbih  = (const float*)d_in[22];
  const float* gbhh  = (const float*)d_in[23];
  float* out = (float*)d_out;

  char* wsp = (char*)d_ws;
  auto take = [&](size_t bytes) -> char* {
    char* p = wsp;
    wsp += (bytes + 255) & ~(size_t)255;
    return p;
  };
  u16* xhi = (u16*)take((size_t)1048576 * 2);
  u16* xlo = (u16*)take((size_t)1048576 * 2);
  float* hf = (float*)take((size_t)M_ * 128 * 4);
  u16* hhi = (u16*)take((size_t)M_ * 128 * 2);
  u16* hlo = (u16*)take((size_t)M_ * 128 * 2);
  char* U = take(33554432);                 // union: qkv planes / ff1 planes
  u16* qkvhi = (u16*)U;
  u16* qkvlo = (u16*)(U + 12582912);
  u16* f1hi = (u16*)U;
  u16* f1lo = (u16*)(U + 16777216);
  u16* vthi = (u16*)take((size_t)2097152 * 2);
  u16* vtlo = (u16*)take((size_t)2097152 * 2);
  u16* ohi = (u16*)take((size_t)2097152 * 2);
  u16* olo = (u16*)take((size_t)2097152 * 2);
  float* gtmp = (float*)take((size_t)M_ * 128 * 4);
  u16* inwhi = (u16*)take(8192 * 2);   u16* inwlo = (u16*)take(8192 * 2);
  u16* qwhi = (u16*)take(196608 * 2);  u16* qwlo = (u16*)take(196608 * 2);
  u16* owhi = (u16*)take(65536 * 2);   u16* owlo = (u16*)take(65536 * 2);
  u16* f1whi = (u16*)take(262144 * 2); u16* f1wlo = (u16*)take(262144 * 2);
  u16* f2whi = (u16*)take(262144 * 2); u16* f2wlo = (u16*)take(262144 * 2);
  float* cnorm = (float*)take(512 * 4);

  k_split<<<4096, 256, 0, stream>>>(x, xhi, xlo, 1048576);
  k_split<<<32, 256, 0, stream>>>(in_w, inwhi, inwlo, 8192);
  k_split<<<768, 256, 0, stream>>>(qkv_w, qwhi, qwlo, 196608);
  k_split<<<256, 256, 0, stream>>>(out_w, owhi, owlo, 65536);
  k_split<<<1024, 256, 0, stream>>>(ff1w, f1whi, f1wlo, 262144);
  k_split<<<1024, 256, 0, stream>>>(ff2w, f2whi, f2wlo, 262144);
  k_cnorm<<<1, 64, 0, stream>>>(cent, cnorm);

  // input projection: h = x @ in_w^T + in_b
  k_gemm<0, 3><<<dim3(128, 2), 256, 0, stream>>>(xhi, xlo, inwhi, inwlo, in_b,
                                                 hf, hhi, hlo, 128, 64);

  for (int l = 0; l < 4; ++l) {
    k_gemm<0, 2><<<dim3(128, 6), 256, 0, stream>>>(
        hhi, hlo, qwhi + l * 49152, qwlo + l * 49152, qkv_b + l * 384,
        nullptr, qkvhi, qkvlo, 384, 128);
    k_vtprep<<<8192, 256, 0, stream>>>(qkvhi, qkvlo, vthi, vtlo);
    k_attn<<<dim3(16, 64), 256, 0, stream>>>(qkvhi, qkvlo, vthi, vtlo, ohi, olo);
    k_gemm<0, 1><<<dim3(128, 2), 256, 0, stream>>>(
        ohi, olo, owhi + l * 16384, owlo + l * 16384, out_b + l * 128,
        gtmp, nullptr, nullptr, 128, 128);
    k_lnadd<<<4096, 256, 0, stream>>>(hf, gtmp, ln1w + l * 128, ln1b + l * 128,
                                      hf, hhi, hlo);
    k_gemm<1, 2><<<dim3(128, 8), 256, 0, stream>>>(
        hhi, hlo, f1whi + l * 65536, f1wlo + l * 65536, ff1b + l * 512,
        nullptr, f1hi, f1lo, 512, 128);
    k_gemm<0, 1><<<dim3(128, 2), 256, 0, stream>>>(
        f1hi, f1lo, f2whi + l * 65536, f2wlo + l * 65536, ff2b + l * 128,
        gtmp, nullptr, nullptr, 128, 512);
    k_lnadd<<<4096, 256, 0, stream>>>(hf, gtmp, ln2w + l * 128, ln2b + l * 128,
                                      hf, hhi, hlo);
  }

  k_head<<<4096, 256, 0, stream>>>(hf, nw, nb, cnorm, temp, out);
  k_gru<<<1, 64, 0, stream>>>(out + OUT_PROBS, init, gwih, gwhh, gbih, gbhh, out);
}

// Round 2
// 869.051 us; speedup vs baseline: 1.2543x; 1.2543x over previous
//
#include <hip/hip_runtime.h>
#include <cstdint>
#include <cstddef>

#define B_    16
#define T_    1024
#define NF_   64
#define D_    128
#define H_    4
#define DFF_  512
#define M_    16384   // B_*T_

#define OUT_SP     0
#define OUT_REG    65536
#define OUT_PROBS  81920
#define OUT_H      147456
#define OUT_FS     2244608

typedef float f32x4 __attribute__((ext_vector_type(4)));
typedef short bf16x8 __attribute__((ext_vector_type(8)));
typedef unsigned short u16;
typedef unsigned int u32;

__device__ __forceinline__ u16 f2b(float v) {
  union { float f; u32 u; } x; x.f = v;
  u32 r = x.u + 0x7fffu + ((x.u >> 16) & 1u);   // RNE to bf16
  return (u16)(r >> 16);
}
__device__ __forceinline__ float b2f(u16 b) {
  union { u32 u; float f; } x; x.u = ((u32)b) << 16; return x.f;
}
__device__ __forceinline__ void gload16(const void* g, void* l) {
  __builtin_amdgcn_global_load_lds((const __attribute__((address_space(1))) void*)g,
                                   (__attribute__((address_space(3))) void*)l, 16, 0, 0);
}
__device__ __forceinline__ f32x4 mfma_bf16(bf16x8 a, bf16x8 b, f32x4 c) {
  return __builtin_amdgcn_mfma_f32_16x16x32_bf16(a, b, c, 0, 0, 0);
}

// quad_perm broadcasts (VALU DPP, ~2cy vs ds_bpermute ~100cy)
__device__ __forceinline__ float qb0(float x) {
  int i = __builtin_bit_cast(int, x);
  i = __builtin_amdgcn_mov_dpp(i, 0x00, 0xf, 0xf, true);
  return __builtin_bit_cast(float, i);
}
__device__ __forceinline__ float qb1(float x) {
  int i = __builtin_bit_cast(int, x);
  i = __builtin_amdgcn_mov_dpp(i, 0x55, 0xf, 0xf, true);
  return __builtin_bit_cast(float, i);
}
__device__ __forceinline__ float qb2(float x) {
  int i = __builtin_bit_cast(int, x);
  i = __builtin_amdgcn_mov_dpp(i, 0xAA, 0xf, 0xf, true);
  return __builtin_bit_cast(float, i);
}
__device__ __forceinline__ float qb3(float x) {
  int i = __builtin_bit_cast(int, x);
  i = __builtin_amdgcn_mov_dpp(i, 0xFF, 0xf, 0xf, true);
  return __builtin_bit_cast(float, i);
}

// ---------------- split fp32 -> (hi, lo) bf16 planes ----------------
__global__ void k_split(const float* __restrict__ s, u16* __restrict__ hi,
                        u16* __restrict__ lo, int n) {
  int i = blockIdx.x * blockDim.x + threadIdx.x;
  if (i >= n) return;
  float v = s[i];
  u16 h = f2b(v);
  hi[i] = h;
  lo[i] = f2b(v - b2f(h));
}

// ---------------- normalized centroids ----------------
__global__ void k_cnorm(const float* __restrict__ c, float* __restrict__ cn) {
  const int lane = threadIdx.x;  // 64
  for (int r = 0; r < 4; ++r) {
    float2 v = *(const float2*)&c[r * 128 + lane * 2];
    float ss = v.x * v.x + v.y * v.y;
#pragma unroll
    for (int d = 1; d < 64; d <<= 1) ss += __shfl_xor(ss, d, 64);
    float nrm = fmaxf(sqrtf(ss), 1e-12f);
    float2 o; o.x = v.x / nrm; o.y = v.y / nrm;
    *(float2*)&cn[r * 128 + lane * 2] = o;
  }
}

// ---------------- split-bf16 GEMM: C[M,N] = A[M,K] @ W[N,K]^T + bias ----------------
// OUTMODE bit0: write fp32 C, bit1: write (hi,lo) planes. RELU optional.
template <int RELU, int OUTMODE>
__global__ __launch_bounds__(256)
void k_gemm(const u16* __restrict__ Ahi, const u16* __restrict__ Alo,
            const u16* __restrict__ Whi, const u16* __restrict__ Wlo,
            const float* __restrict__ bias,
            float* __restrict__ Cf, u16* __restrict__ Chi, u16* __restrict__ Clo,
            int N, int K) {
  __shared__ u16 lA[2][128 * 32];
  __shared__ u16 lB[2][64 * 32];
  const int tid = threadIdx.x;
  const int wv = tid >> 6, lane = tid & 63;
  const int lo16 = lane & 15, hi2 = lane >> 4;
  const int m0 = blockIdx.x * 128, n0 = blockIdx.y * 64;
  const int ar = tid >> 2, ac = (tid & 3) * 8;

  f32x4 acc[2][4];
#pragma unroll
  for (int i = 0; i < 2; ++i)
#pragma unroll
    for (int j = 0; j < 4; ++j) acc[i][j] = (f32x4){0.f, 0.f, 0.f, 0.f};

  for (int k0 = 0; k0 < K; k0 += 32) {
    __syncthreads();
    gload16(Ahi + (size_t)(m0 + ar) * K + k0 + ac,      &lA[0][ar * 32 + ac]);
    gload16(Ahi + (size_t)(m0 + 64 + ar) * K + k0 + ac, &lA[0][(64 + ar) * 32 + ac]);
    gload16(Alo + (size_t)(m0 + ar) * K + k0 + ac,      &lA[1][ar * 32 + ac]);
    gload16(Alo + (size_t)(m0 + 64 + ar) * K + k0 + ac, &lA[1][(64 + ar) * 32 + ac]);
    gload16(Whi + (size_t)(n0 + ar) * K + k0 + ac,      &lB[0][ar * 32 + ac]);
    gload16(Wlo + (size_t)(n0 + ar) * K + k0 + ac,      &lB[1][ar * 32 + ac]);
    __syncthreads();

    bf16x8 af[2][2], bf[4][2];
#pragma unroll
    for (int rt = 0; rt < 2; ++rt)
#pragma unroll
      for (int p = 0; p < 2; ++p)
        af[rt][p] = *(const bf16x8*)&lA[p][(wv * 32 + rt * 16 + lo16) * 32 + hi2 * 8];
#pragma unroll
    for (int ct = 0; ct < 4; ++ct)
#pragma unroll
      for (int p = 0; p < 2; ++p)
        bf[ct][p] = *(const bf16x8*)&lB[p][(ct * 16 + lo16) * 32 + hi2 * 8];
#pragma unroll
    for (int rt = 0; rt < 2; ++rt)
#pragma unroll
      for (int ct = 0; ct < 4; ++ct) {
        acc[rt][ct] = mfma_bf16(af[rt][0], bf[ct][0], acc[rt][ct]);
        acc[rt][ct] = mfma_bf16(af[rt][0], bf[ct][1], acc[rt][ct]);
        acc[rt][ct] = mfma_bf16(af[rt][1], bf[ct][0], acc[rt][ct]);
      }
  }

#pragma unroll
  for (int rt = 0; rt < 2; ++rt)
#pragma unroll
    for (int ct = 0; ct < 4; ++ct) {
      const int col = n0 + ct * 16 + lo16;
      const float bc = bias[col];
#pragma unroll
      for (int r = 0; r < 4; ++r) {
        const int row = m0 + wv * 32 + rt * 16 + hi2 * 4 + r;
        float v = acc[rt][ct][r] + bc;
        if (RELU) v = fmaxf(v, 0.f);
        const size_t idx = (size_t)row * N + col;
        if (OUTMODE & 1) Cf[idx] = v;
        if (OUTMODE & 2) {
          u16 hb = f2b(v);
          Chi[idx] = hb;
          Clo[idx] = f2b(v - b2f(hb));
        }
      }
    }
}

// ---------------- V transpose prep: Vt[b,h,d,t] from qkv[b,t,256+h*32+d] ----------------
__global__ void k_vtprep(const u16* __restrict__ qh, const u16* __restrict__ ql,
                         u16* __restrict__ vh, u16* __restrict__ vl) {
  int i = blockIdx.x * 256 + threadIdx.x;  // 0..2M-1
  int t = i & 1023;
  int d = (i >> 10) & 31;
  int bh = i >> 15;
  int b = bh >> 2, hh = bh & 3;
  size_t src = ((size_t)(b * 1024 + t)) * 384 + 256 + hh * 32 + d;
  size_t dst = ((size_t)(bh * 32 + d)) * 1024 + t;
  vh[dst] = qh[src];
  vl[dst] = ql[src];
}

// ---------------- flash attention, split-bf16 MFMA ----------------
__global__ __launch_bounds__(256)
void k_attn(const u16* __restrict__ qkh, const u16* __restrict__ qkl,
            const u16* __restrict__ vth, const u16* __restrict__ vtl,
            u16* __restrict__ ohi, u16* __restrict__ olo) {
  __shared__ u16 lQ[2][64 * 32];
  __shared__ u16 lK[2][64 * 32];
  __shared__ u16 lV[2][32 * 64];
  __shared__ float lP[4][16 * 64];

  const int tid = threadIdx.x;
  const int wv = tid >> 6, lane = tid & 63;
  const int lo16 = lane & 15, hi2 = lane >> 4;
  const int qt = blockIdx.x;   // 0..15
  const int bh = blockIdx.y;   // 0..63
  const int b = bh >> 2, h = bh & 3;
  const int ar = tid >> 2, ac = (tid & 3) * 8;

  const size_t qrow0 = (size_t)b * T_ + qt * 64;
  gload16(qkh + (qrow0 + ar) * 384 + h * 32 + ac, &lQ[0][ar * 32 + ac]);
  gload16(qkl + (qrow0 + ar) * 384 + h * 32 + ac, &lQ[1][ar * 32 + ac]);
  __syncthreads();
  bf16x8 qf0 = *(const bf16x8*)&lQ[0][(wv * 16 + lo16) * 32 + hi2 * 8];
  bf16x8 qf1 = *(const bf16x8*)&lQ[1][(wv * 16 + lo16) * 32 + hi2 * 8];

  f32x4 oacc[2];
  oacc[0] = (f32x4){0.f, 0.f, 0.f, 0.f};
  oacc[1] = (f32x4){0.f, 0.f, 0.f, 0.f};
  float mrow[4] = {-1e30f, -1e30f, -1e30f, -1e30f};
  float lrow[4] = {0.f, 0.f, 0.f, 0.f};
  const float scale = 0.17677669529663687f;  // 1/sqrt(32)

  for (int kt = 0; kt < 16; ++kt) {
    __syncthreads();
    const size_t krow0 = (size_t)b * T_ + kt * 64;
    gload16(qkh + (krow0 + ar) * 384 + 128 + h * 32 + ac, &lK[0][ar * 32 + ac]);
    gload16(qkl + (krow0 + ar) * 384 + 128 + h * 32 + ac, &lK[1][ar * 32 + ac]);
    const size_t vrow = ((size_t)bh * 32 + (tid >> 3)) * T_ + kt * 64 + (tid & 7) * 8;
    gload16(vth + vrow, &lV[0][(tid >> 3) * 64 + (tid & 7) * 8]);
    gload16(vtl + vrow, &lV[1][(tid >> 3) * 64 + (tid & 7) * 8]);
    __syncthreads();

    f32x4 s[4];
#pragma unroll
    for (int ct = 0; ct < 4; ++ct) {
      bf16x8 kf0 = *(const bf16x8*)&lK[0][(ct * 16 + lo16) * 32 + hi2 * 8];
      bf16x8 kf1 = *(const bf16x8*)&lK[1][(ct * 16 + lo16) * 32 + hi2 * 8];
      f32x4 z = (f32x4){0.f, 0.f, 0.f, 0.f};
      z = mfma_bf16(qf0, kf0, z);
      z = mfma_bf16(qf0, kf1, z);
      z = mfma_bf16(qf1, kf0, z);
      s[ct] = z;
    }
#pragma unroll
    for (int r = 0; r < 4; ++r) {
      float v0 = s[0][r] * scale, v1 = s[1][r] * scale;
      float v2 = s[2][r] * scale, v3 = s[3][r] * scale;
      float mx = fmaxf(fmaxf(v0, v1), fmaxf(v2, v3));
#pragma unroll
      for (int d2 = 1; d2 < 16; d2 <<= 1) mx = fmaxf(mx, __shfl_xor(mx, d2, 64));
      float mnew = fmaxf(mrow[r], mx);
      float corr = __expf(mrow[r] - mnew);
      mrow[r] = mnew;
      float p0 = __expf(v0 - mnew), p1 = __expf(v1 - mnew);
      float p2 = __expf(v2 - mnew), p3 = __expf(v3 - mnew);
      float rs = p0 + p1 + p2 + p3;
#pragma unroll
      for (int d2 = 1; d2 < 16; d2 <<= 1) rs += __shfl_xor(rs, d2, 64);
      lrow[r] = lrow[r] * corr + rs;
      oacc[0][r] *= corr;
      oacc[1][r] *= corr;
      const int prow = hi2 * 4 + r;
      lP[wv][prow * 64 + 0 * 16 + lo16] = p0;
      lP[wv][prow * 64 + 1 * 16 + lo16] = p1;
      lP[wv][prow * 64 + 2 * 16 + lo16] = p2;
      lP[wv][prow * 64 + 3 * 16 + lo16] = p3;
    }
    // intra-wave LDS write->read hazard: drain DS queue before cross-lane read
    asm volatile("s_waitcnt lgkmcnt(0)" ::: "memory");
#pragma unroll
    for (int c = 0; c < 2; ++c) {
      const float* pp = &lP[wv][lo16 * 64 + c * 32 + hi2 * 8];
      float4 pa = *(const float4*)pp;
      float4 pb = *(const float4*)(pp + 4);
      float pv[8] = {pa.x, pa.y, pa.z, pa.w, pb.x, pb.y, pb.z, pb.w};
      bf16x8 ph, pl;
#pragma unroll
      for (int j = 0; j < 8; ++j) {
        u16 hb = f2b(pv[j]);
        ph[j] = (short)hb;
        pl[j] = (short)f2b(pv[j] - b2f(hb));
      }
#pragma unroll
      for (int ct2 = 0; ct2 < 2; ++ct2) {
        bf16x8 vf0 = *(const bf16x8*)&lV[0][(ct2 * 16 + lo16) * 64 + c * 32 + hi2 * 8];
        bf16x8 vf1 = *(const bf16x8*)&lV[1][(ct2 * 16 + lo16) * 64 + c * 32 + hi2 * 8];
        oacc[ct2] = mfma_bf16(ph, vf0, oacc[ct2]);
        oacc[ct2] = mfma_bf16(ph, vf1, oacc[ct2]);
        oacc[ct2] = mfma_bf16(pl, vf0, oacc[ct2]);
      }
    }
  }
#pragma unroll
  for (int ct2 = 0; ct2 < 2; ++ct2)
#pragma unroll
    for (int r = 0; r < 4; ++r) {
      float v = oacc[ct2][r] / lrow[r];
      const int t = qt * 64 + wv * 16 + hi2 * 4 + r;
      const size_t idx = ((size_t)b * T_ + t) * D_ + h * 32 + ct2 * 16 + lo16;
      u16 hb = f2b(v);
      ohi[idx] = hb;
      olo[idx] = f2b(v - b2f(hb));
    }
}

// ---------------- fused residual add + LayerNorm ----------------
__global__ __launch_bounds__(256)
void k_lnadd(const float* hin, const float* __restrict__ add,
             const float* __restrict__ w, const float* __restrict__ b,
             float* hout, u16* __restrict__ hhi, u16* __restrict__ hlo) {
  const int row = blockIdx.x * 4 + (threadIdx.x >> 6);
  const int lane = threadIdx.x & 63;
  const size_t base = (size_t)row * D_ + lane * 2;
  float2 x = *(const float2*)(hin + base);
  float2 a = *(const float2*)(add + base);
  x.x += a.x; x.y += a.y;
  float s = x.x + x.y;
#pragma unroll
  for (int d2 = 1; d2 < 64; d2 <<= 1) s += __shfl_xor(s, d2, 64);
  const float m = s * (1.f / 128.f);
  float dx = x.x - m, dy = x.y - m;
  float q = dx * dx + dy * dy;
#pragma unroll
  for (int d2 = 1; d2 < 64; d2 <<= 1) q += __shfl_xor(q, d2, 64);
  const float inv = rsqrtf(q * (1.f / 128.f) + 1e-5f);
  const float2 ww = *(const float2*)(w + lane * 2);
  const float2 bb = *(const float2*)(b + lane * 2);
  float y0 = dx * inv * ww.x + bb.x;
  float y1 = dy * inv * ww.y + bb.y;
  float2 yo; yo.x = y0; yo.y = y1;
  *(float2*)(hout + base) = yo;
  u16 h0 = f2b(y0), h1 = f2b(y1);
  u16 l0 = f2b(y0 - b2f(h0)), l1 = f2b(y1 - b2f(h1));
  *(u32*)(hhi + base) = (u32)h0 | ((u32)h1 << 16);
  *(u32*)(hlo + base) = (u32)l0 | ((u32)l1 << 16);
}

// ---------------- head: final LN -> h out, cosine logits -> probs out + GRU gi precompute ----------------
__global__ __launch_bounds__(256)
void k_head(const float* __restrict__ hin, const float* __restrict__ w,
            const float* __restrict__ bws, const float* __restrict__ cn,
            const float* __restrict__ temp,
            const float* __restrict__ wih, const float* __restrict__ bih,
            float4* __restrict__ g4, float* __restrict__ out) {
  const int row = blockIdx.x * 4 + (threadIdx.x >> 6);
  const int lane = threadIdx.x & 63;
  const size_t base = (size_t)row * D_ + lane * 2;
  float2 x = *(const float2*)(hin + base);
  float s = x.x + x.y;
#pragma unroll
  for (int d2 = 1; d2 < 64; d2 <<= 1) s += __shfl_xor(s, d2, 64);
  float m = s * (1.f / 128.f);
  float dx = x.x - m, dy = x.y - m;
  float q = dx * dx + dy * dy;
#pragma unroll
  for (int d2 = 1; d2 < 64; d2 <<= 1) q += __shfl_xor(q, d2, 64);
  float inv = rsqrtf(q * (1.f / 128.f) + 1e-5f);
  float2 ww = *(const float2*)(w + lane * 2);
  float2 bb = *(const float2*)(bws + lane * 2);
  float y0 = dx * inv * ww.x + bb.x;
  float y1 = dy * inv * ww.y + bb.y;
  float2 yo; yo.x = y0; yo.y = y1;
  *(float2*)(out + OUT_H + base) = yo;
  float ss = y0 * y0 + y1 * y1;
#pragma unroll
  for (int d2 = 1; d2 < 64; d2 <<= 1) ss += __shfl_xor(ss, d2, 64);
  float nrm = fmaxf(sqrtf(ss), 1e-12f);
  float z0 = y0 / nrm, z1 = y1 / nrm;
  float lg[4];
#pragma unroll
  for (int rr = 0; rr < 4; ++rr)
    lg[rr] = z0 * cn[rr * 128 + lane * 2] + z1 * cn[rr * 128 + lane * 2 + 1];
#pragma unroll
  for (int d2 = 1; d2 < 64; d2 <<= 1) {
#pragma unroll
    for (int rr = 0; rr < 4; ++rr) lg[rr] += __shfl_xor(lg[rr], d2, 64);
  }
  float ts = 1.f / fmaxf(temp[0], 1e-4f);
#pragma unroll
  for (int rr = 0; rr < 4; ++rr) lg[rr] *= ts;
  float mx = fmaxf(fmaxf(lg[0], lg[1]), fmaxf(lg[2], lg[3]));
  float e0 = __expf(lg[0] - mx), e1 = __expf(lg[1] - mx);
  float e2 = __expf(lg[2] - mx), e3 = __expf(lg[3] - mx);
  float es = e0 + e1 + e2 + e3;
  float einv = 1.f / es;
  float p0 = e0 * einv, p1 = e1 * einv, p2 = e2 * einv, p3 = e3 * einv;
  if (lane < 4) {
    float pr = (lane == 0) ? p0 : (lane == 1) ? p1 : (lane == 2) ? p2 : p3;
    out[OUT_PROBS + (size_t)row * 4 + lane] = pr;
    // GRU input-gate preactivations gi[g] = bih[g*4+r] + wih[g*4+r,:] @ p
    float gi[3];
#pragma unroll
    for (int g = 0; g < 3; ++g) {
      const float* wr = wih + (g * 4 + lane) * 4;
      gi[g] = bih[g * 4 + lane] + wr[0] * p0 + wr[1] * p1 + wr[2] * p2 + wr[3] * p3;
    }
    const int b = row >> 10, t = row & 1023;
    float4 o4;
    o4.x = gi[0]; o4.y = gi[1]; o4.z = gi[2]; o4.w = pr;
    g4[(size_t)t * 64 + b * 4 + lane] = o4;
  }
}

// ---------------- sequential GRU smoothing scan (single wave, DPP, no LDS) ----------------
__global__ __launch_bounds__(64)
void k_scan(const float4* __restrict__ g4, const float* __restrict__ init,
            const float* __restrict__ whh, const float* __restrict__ bhh,
            float* __restrict__ out) {
  const int tid = threadIdx.x;
  const int r = tid & 3, b = tid >> 2;
  float Wh[3][4], Bh[3];
#pragma unroll
  for (int g = 0; g < 3; ++g) {
    Bh[g] = bhh[g * 4 + r];
#pragma unroll
    for (int j = 0; j < 4; ++j) Wh[g][j] = whh[(g * 4 + r) * 4 + j];
  }
  float st = init[tid];
  float* osp = out + OUT_SP + (size_t)b * 4096 + r;

  float4 pre[4];
#pragma unroll
  for (int d = 0; d < 4; ++d) pre[d] = g4[d * 64 + tid];

  for (int tc = 0; tc < 1024; tc += 4) {
#pragma unroll
    for (int d = 0; d < 4; ++d) {
      float4 v = pre[d];
      const int tn = tc + 4 + d;
      if (tn < 1024) pre[d] = g4[(size_t)tn * 64 + tid];   // prefetch ~4 steps (~400cy) ahead
      // broadcast quad state via DPP (VALU pipe)
      float s0 = qb0(st), s1 = qb1(st), s2 = qb2(st), s3 = qb3(st);
      float gh0 = fmaf(Wh[0][3], s3, fmaf(Wh[0][2], s2, fmaf(Wh[0][1], s1, fmaf(Wh[0][0], s0, Bh[0]))));
      float gh1 = fmaf(Wh[1][3], s3, fmaf(Wh[1][2], s2, fmaf(Wh[1][1], s1, fmaf(Wh[1][0], s0, Bh[1]))));
      float gh2 = fmaf(Wh[2][3], s3, fmaf(Wh[2][2], s2, fmaf(Wh[2][1], s1, fmaf(Wh[2][0], s0, Bh[2]))));
      float rg = __builtin_amdgcn_rcpf(1.f + __expf(-(v.x + gh0)));
      float zg = __builtin_amdgcn_rcpf(1.f + __expf(-(v.y + gh1)));
      float nx = fmaf(rg, gh2, v.z);
      float ex = __expf(2.f * nx);
      float ng = 1.f - 2.f * __builtin_amdgcn_rcpf(ex + 1.f);
      float sn = fmaf(zg, st - ng, ng);            // (1-z)*n + z*s
      sn = fmaf(0.9f, sn, 0.1f * v.w);             // temporal smoothing
      st = sn;
      osp[(size_t)(tc + d) * 4] = sn;
    }
  }
  out[OUT_FS + tid] = st;
}

// ---------------- argmax over smoothed probs ----------------
__global__ __launch_bounds__(256)
void k_argmax(const float* __restrict__ sp, float* __restrict__ reg) {
  int i = blockIdx.x * 256 + threadIdx.x;   // 0..16383
  float4 v = *(const float4*)&sp[(size_t)i * 4];
  int am = 0; float bv = v.x;
  if (v.y > bv) { bv = v.y; am = 1; }
  if (v.z > bv) { bv = v.z; am = 2; }
  if (v.w > bv) { bv = v.w; am = 3; }
  reg[i] = (float)am;
}

// ---------------- launch ----------------
extern "C" void kernel_launch(void* const* d_in, const int* in_sizes, int n_in,
                              void* d_out, int out_size, void* d_ws, size_t ws_size,
                              hipStream_t stream) {
  (void)in_sizes; (void)n_in; (void)out_size; (void)ws_size;
  const float* x     = (const float*)d_in[0];
  const float* init  = (const float*)d_in[1];
  const float* in_w  = (const float*)d_in[2];
  const float* in_b  = (const float*)d_in[3];
  const float* qkv_w = (const float*)d_in[4];
  const float* qkv_b = (const float*)d_in[5];
  const float* out_w = (const float*)d_in[6];
  const float* out_b = (const float*)d_in[7];
  const float* ln1w  = (const float*)d_in[8];
  const float* ln1b  = (const float*)d_in[9];
  const float* ff1w  = (const float*)d_in[10];
  const float* ff1b  = (const float*)d_in[11];
  const float* ff2w  = (const float*)d_in[12];
  const float* ff2b  = (const float*)d_in[13];
  const float* ln2w  = (const float*)d_in[14];
  const float* ln2b  = (const float*)d_in[15];
  const float* nw    = (const float*)d_in[16];
  const float* nb    = (const float*)d_in[17];
  const float* cent  = (const float*)d_in[18];
  const float* temp  = (const float*)d_in[19];
  const float* gwih  = (const float*)d_in[20];
  const float* gwhh  = (const float*)d_in[21];
  const float* gbih  = (const float*)d_in[22];
  const float* gbhh  = (const float*)d_in[23];
  float* out = (float*)d_out;

  char* wsp = (char*)d_ws;
  auto take = [&](size_t bytes) -> char* {
    char* p = wsp;
    wsp += (bytes + 255) & ~(size_t)255;
    return p;
  };
  u16* xhi = (u16*)take((size_t)1048576 * 2);
  u16* xlo = (u16*)take((size_t)1048576 * 2);
  float* hf = (float*)take((size_t)M_ * 128 * 4);
  u16* hhi = (u16*)take((size_t)M_ * 128 * 2);
  u16* hlo = (u16*)take((size_t)M_ * 128 * 2);
  char* U = take(33554432);                 // union: qkv planes / ff1 planes
  u16* qkvhi = (u16*)U;
  u16* qkvlo = (u16*)(U + 12582912);
  u16* f1hi = (u16*)U;
  u16* f1lo = (u16*)(U + 16777216);
  u16* vthi = (u16*)take((size_t)2097152 * 2);
  u16* vtlo = (u16*)take((size_t)2097152 * 2);
  u16* ohi = (u16*)take((size_t)2097152 * 2);
  u16* olo = (u16*)take((size_t)2097152 * 2);
  float* gtmp = (float*)take((size_t)M_ * 128 * 4);
  u16* inwhi = (u16*)take(8192 * 2);   u16* inwlo = (u16*)take(8192 * 2);
  u16* qwhi = (u16*)take(196608 * 2);  u16* qwlo = (u16*)take(196608 * 2);
  u16* owhi = (u16*)take(65536 * 2);   u16* owlo = (u16*)take(65536 * 2);
  u16* f1whi = (u16*)take(262144 * 2); u16* f1wlo = (u16*)take(262144 * 2);
  u16* f2whi = (u16*)take(262144 * 2); u16* f2wlo = (u16*)take(262144 * 2);
  float* cnorm = (float*)take(512 * 4);
  float4* g4 = (float4*)take((size_t)T_ * 64 * 16);   // {gi_r, gi_z, gi_n, p} per (t, b, r)

  k_split<<<4096, 256, 0, stream>>>(x, xhi, xlo, 1048576);
  k_split<<<32, 256, 0, stream>>>(in_w, inwhi, inwlo, 8192);
  k_split<<<768, 256, 0, stream>>>(qkv_w, qwhi, qwlo, 196608);
  k_split<<<256, 256, 0, stream>>>(out_w, owhi, owlo, 65536);
  k_split<<<1024, 256, 0, stream>>>(ff1w, f1whi, f1wlo, 262144);
  k_split<<<1024, 256, 0, stream>>>(ff2w, f2whi, f2wlo, 262144);
  k_cnorm<<<1, 64, 0, stream>>>(cent, cnorm);

  // input projection: h = x @ in_w^T + in_b
  k_gemm<0, 3><<<dim3(128, 2), 256, 0, stream>>>(xhi, xlo, inwhi, inwlo, in_b,
                                                 hf, hhi, hlo, 128, 64);

  for (int l = 0; l < 4; ++l) {
    k_gemm<0, 2><<<dim3(128, 6), 256, 0, stream>>>(
        hhi, hlo, qwhi + l * 49152, qwlo + l * 49152, qkv_b + l * 384,
        nullptr, qkvhi, qkvlo, 384, 128);
    k_vtprep<<<8192, 256, 0, stream>>>(qkvhi, qkvlo, vthi, vtlo);
    k_attn<<<dim3(16, 64), 256, 0, stream>>>(qkvhi, qkvlo, vthi, vtlo, ohi, olo);
    k_gemm<0, 1><<<dim3(128, 2), 256, 0, stream>>>(
        ohi, olo, owhi + l * 16384, owlo + l * 16384, out_b + l * 128,
        gtmp, nullptr, nullptr, 128, 128);
    k_lnadd<<<4096, 256, 0, stream>>>(hf, gtmp, ln1w + l * 128, ln1b + l * 128,
                                      hf, hhi, hlo);
    k_gemm<1, 2><<<dim3(128, 8), 256, 0, stream>>>(
        hhi, hlo, f1whi + l * 65536, f1wlo + l * 65536, ff1b + l * 512,
        nullptr, f1hi, f1lo, 512, 128);
    k_gemm<0, 1><<<dim3(128, 2), 256, 0, stream>>>(
        f1hi, f1lo, f2whi + l * 65536, f2wlo + l * 65536, ff2b + l * 128,
        gtmp, nullptr, nullptr, 128, 512);
    k_lnadd<<<4096, 256, 0, stream>>>(hf, gtmp, ln2w + l * 128, ln2b + l * 128,
                                      hf, hhi, hlo);
  }

  k_head<<<4096, 256, 0, stream>>>(hf, nw, nb, cnorm, temp, gwih, gbih, g4, out);
  k_scan<<<1, 64, 0, stream>>>(g4, init, gwhh, gbhh, out);
  k_argmax<<<64, 256, 0, stream>>>(out + OUT_SP, out + OUT_REG);
}

// Round 3
// 836.616 us; speedup vs baseline: 1.3029x; 1.0388x over previous
//
#include <hip/hip_runtime.h>
#include <cstdint>
#include <cstddef>

#define B_    16
#define T_    1024
#define NF_   64
#define D_    128
#define H_    4
#define DFF_  512
#define M_    16384   // B_*T_

#define OUT_SP     0
#define OUT_REG    65536
#define OUT_PROBS  81920
#define OUT_H      147456
#define OUT_FS     2244608

#define LOG2E 1.4426950408889634f

typedef float f32x4 __attribute__((ext_vector_type(4)));
typedef short bf16x8 __attribute__((ext_vector_type(8)));
typedef unsigned short u16;
typedef unsigned int u32;

__device__ __forceinline__ u16 f2b(float v) {
  union { float f; u32 u; } x; x.f = v;
  u32 r = x.u + 0x7fffu + ((x.u >> 16) & 1u);   // RNE to bf16
  return (u16)(r >> 16);
}
__device__ __forceinline__ float b2f(u16 b) {
  union { u32 u; float f; } x; x.u = ((u32)b) << 16; return x.f;
}
__device__ __forceinline__ void gload16(const void* g, void* l) {
  __builtin_amdgcn_global_load_lds((const __attribute__((address_space(1))) void*)g,
                                   (__attribute__((address_space(3))) void*)l, 16, 0, 0);
}
__device__ __forceinline__ f32x4 mfma_bf16(bf16x8 a, bf16x8 b, f32x4 c) {
  return __builtin_amdgcn_mfma_f32_16x16x32_bf16(a, b, c, 0, 0, 0);
}

// quad_perm broadcasts (VALU DPP, ~2cy vs ds_bpermute ~100cy)
__device__ __forceinline__ float qb0(float x) {
  int i = __builtin_bit_cast(int, x);
  i = __builtin_amdgcn_mov_dpp(i, 0x00, 0xf, 0xf, true);
  return __builtin_bit_cast(float, i);
}
__device__ __forceinline__ float qb1(float x) {
  int i = __builtin_bit_cast(int, x);
  i = __builtin_amdgcn_mov_dpp(i, 0x55, 0xf, 0xf, true);
  return __builtin_bit_cast(float, i);
}
__device__ __forceinline__ float qb2(float x) {
  int i = __builtin_bit_cast(int, x);
  i = __builtin_amdgcn_mov_dpp(i, 0xAA, 0xf, 0xf, true);
  return __builtin_bit_cast(float, i);
}
__device__ __forceinline__ float qb3(float x) {
  int i = __builtin_bit_cast(int, x);
  i = __builtin_amdgcn_mov_dpp(i, 0xFF, 0xf, 0xf, true);
  return __builtin_bit_cast(float, i);
}

// ---------------- split fp32 -> (hi, lo) bf16 planes ----------------
__global__ void k_split(const float* __restrict__ s, u16* __restrict__ hi,
                        u16* __restrict__ lo, int n) {
  int i = blockIdx.x * blockDim.x + threadIdx.x;
  if (i >= n) return;
  float v = s[i];
  u16 h = f2b(v);
  hi[i] = h;
  lo[i] = f2b(v - b2f(h));
}

// ---------------- normalized centroids ----------------
__global__ void k_cnorm(const float* __restrict__ c, float* __restrict__ cn) {
  const int lane = threadIdx.x;  // 64
  for (int r = 0; r < 4; ++r) {
    float2 v = *(const float2*)&c[r * 128 + lane * 2];
    float ss = v.x * v.x + v.y * v.y;
#pragma unroll
    for (int d = 1; d < 64; d <<= 1) ss += __shfl_xor(ss, d, 64);
    float nrm = fmaxf(sqrtf(ss), 1e-12f);
    float2 o; o.x = v.x / nrm; o.y = v.y / nrm;
    *(float2*)&cn[r * 128 + lane * 2] = o;
  }
}

// ---------------- split-bf16 GEMM: C[M,N] = A[M,K] @ W[N,K]^T + bias ----------------
// OUTMODE bit0: write fp32 C, bit1: write (hi,lo) planes. RELU optional.
template <int RELU, int OUTMODE>
__global__ __launch_bounds__(256)
void k_gemm(const u16* __restrict__ Ahi, const u16* __restrict__ Alo,
            const u16* __restrict__ Whi, const u16* __restrict__ Wlo,
            const float* __restrict__ bias,
            float* __restrict__ Cf, u16* __restrict__ Chi, u16* __restrict__ Clo,
            int N, int K) {
  __shared__ u16 lA[2][128 * 32];
  __shared__ u16 lB[2][64 * 32];
  const int tid = threadIdx.x;
  const int wv = tid >> 6, lane = tid & 63;
  const int lo16 = lane & 15, hi2 = lane >> 4;
  const int m0 = blockIdx.x * 128, n0 = blockIdx.y * 64;
  const int ar = tid >> 2, ac = (tid & 3) * 8;

  f32x4 acc[2][4];
#pragma unroll
  for (int i = 0; i < 2; ++i)
#pragma unroll
    for (int j = 0; j < 4; ++j) acc[i][j] = (f32x4){0.f, 0.f, 0.f, 0.f};

  for (int k0 = 0; k0 < K; k0 += 32) {
    __syncthreads();
    gload16(Ahi + (size_t)(m0 + ar) * K + k0 + ac,      &lA[0][ar * 32 + ac]);
    gload16(Ahi + (size_t)(m0 + 64 + ar) * K + k0 + ac, &lA[0][(64 + ar) * 32 + ac]);
    gload16(Alo + (size_t)(m0 + ar) * K + k0 + ac,      &lA[1][ar * 32 + ac]);
    gload16(Alo + (size_t)(m0 + 64 + ar) * K + k0 + ac, &lA[1][(64 + ar) * 32 + ac]);
    gload16(Whi + (size_t)(n0 + ar) * K + k0 + ac,      &lB[0][ar * 32 + ac]);
    gload16(Wlo + (size_t)(n0 + ar) * K + k0 + ac,      &lB[1][ar * 32 + ac]);
    __syncthreads();

    bf16x8 af[2][2], bf[4][2];
#pragma unroll
    for (int rt = 0; rt < 2; ++rt)
#pragma unroll
      for (int p = 0; p < 2; ++p)
        af[rt][p] = *(const bf16x8*)&lA[p][(wv * 32 + rt * 16 + lo16) * 32 + hi2 * 8];
#pragma unroll
    for (int ct = 0; ct < 4; ++ct)
#pragma unroll
      for (int p = 0; p < 2; ++p)
        bf[ct][p] = *(const bf16x8*)&lB[p][(ct * 16 + lo16) * 32 + hi2 * 8];
#pragma unroll
    for (int rt = 0; rt < 2; ++rt)
#pragma unroll
      for (int ct = 0; ct < 4; ++ct) {
        acc[rt][ct] = mfma_bf16(af[rt][0], bf[ct][0], acc[rt][ct]);
        acc[rt][ct] = mfma_bf16(af[rt][0], bf[ct][1], acc[rt][ct]);
        acc[rt][ct] = mfma_bf16(af[rt][1], bf[ct][0], acc[rt][ct]);
      }
  }

#pragma unroll
  for (int rt = 0; rt < 2; ++rt)
#pragma unroll
    for (int ct = 0; ct < 4; ++ct) {
      const int col = n0 + ct * 16 + lo16;
      const float bc = bias[col];
#pragma unroll
      for (int r = 0; r < 4; ++r) {
        const int row = m0 + wv * 32 + rt * 16 + hi2 * 4 + r;
        float v = acc[rt][ct][r] + bc;
        if (RELU) v = fmaxf(v, 0.f);
        const size_t idx = (size_t)row * N + col;
        if (OUTMODE & 1) Cf[idx] = v;
        if (OUTMODE & 2) {
          u16 hb = f2b(v);
          Chi[idx] = hb;
          Clo[idx] = f2b(v - b2f(hb));
        }
      }
    }
}

// ---------------- V transpose prep: Vt[b,h,d,t] from qkv[b,t,256+h*32+d] ----------------
__global__ void k_vtprep(const u16* __restrict__ qh, const u16* __restrict__ ql,
                         u16* __restrict__ vh, u16* __restrict__ vl) {
  int i = blockIdx.x * 256 + threadIdx.x;  // 0..2M-1
  int t = i & 1023;
  int d = (i >> 10) & 31;
  int bh = i >> 15;
  int b = bh >> 2, hh = bh & 3;
  size_t src = ((size_t)(b * 1024 + t)) * 384 + 256 + hh * 32 + d;
  size_t dst = ((size_t)(bh * 32 + d)) * 1024 + t;
  vh[dst] = qh[src];
  vl[dst] = ql[src];
}

// ---------------- flash attention, split-bf16 MFMA ----------------
__global__ __launch_bounds__(256)
void k_attn(const u16* __restrict__ qkh, const u16* __restrict__ qkl,
            const u16* __restrict__ vth, const u16* __restrict__ vtl,
            u16* __restrict__ ohi, u16* __restrict__ olo) {
  __shared__ u16 lQ[2][64 * 32];
  __shared__ u16 lK[2][64 * 32];
  __shared__ u16 lV[2][32 * 64];
  __shared__ float lP[4][16 * 64];

  const int tid = threadIdx.x;
  const int wv = tid >> 6, lane = tid & 63;
  const int lo16 = lane & 15, hi2 = lane >> 4;
  const int qt = blockIdx.x;   // 0..15
  const int bh = blockIdx.y;   // 0..63
  const int b = bh >> 2, h = bh & 3;
  const int ar = tid >> 2, ac = (tid & 3) * 8;

  const size_t qrow0 = (size_t)b * T_ + qt * 64;
  gload16(qkh + (qrow0 + ar) * 384 + h * 32 + ac, &lQ[0][ar * 32 + ac]);
  gload16(qkl + (qrow0 + ar) * 384 + h * 32 + ac, &lQ[1][ar * 32 + ac]);
  __syncthreads();
  bf16x8 qf0 = *(const bf16x8*)&lQ[0][(wv * 16 + lo16) * 32 + hi2 * 8];
  bf16x8 qf1 = *(const bf16x8*)&lQ[1][(wv * 16 + lo16) * 32 + hi2 * 8];

  f32x4 oacc[2];
  oacc[0] = (f32x4){0.f, 0.f, 0.f, 0.f};
  oacc[1] = (f32x4){0.f, 0.f, 0.f, 0.f};
  float mrow[4] = {-1e30f, -1e30f, -1e30f, -1e30f};
  float lrow[4] = {0.f, 0.f, 0.f, 0.f};
  const float scale = 0.17677669529663687f;  // 1/sqrt(32)

  for (int kt = 0; kt < 16; ++kt) {
    __syncthreads();
    const size_t krow0 = (size_t)b * T_ + kt * 64;
    gload16(qkh + (krow0 + ar) * 384 + 128 + h * 32 + ac, &lK[0][ar * 32 + ac]);
    gload16(qkl + (krow0 + ar) * 384 + 128 + h * 32 + ac, &lK[1][ar * 32 + ac]);
    const size_t vrow = ((size_t)bh * 32 + (tid >> 3)) * T_ + kt * 64 + (tid & 7) * 8;
    gload16(vth + vrow, &lV[0][(tid >> 3) * 64 + (tid & 7) * 8]);
    gload16(vtl + vrow, &lV[1][(tid >> 3) * 64 + (tid & 7) * 8]);
    __syncthreads();

    f32x4 s[4];
#pragma unroll
    for (int ct = 0; ct < 4; ++ct) {
      bf16x8 kf0 = *(const bf16x8*)&lK[0][(ct * 16 + lo16) * 32 + hi2 * 8];
      bf16x8 kf1 = *(const bf16x8*)&lK[1][(ct * 16 + lo16) * 32 + hi2 * 8];
      f32x4 z = (f32x4){0.f, 0.f, 0.f, 0.f};
      z = mfma_bf16(qf0, kf0, z);
      z = mfma_bf16(qf0, kf1, z);
      z = mfma_bf16(qf1, kf0, z);
      s[ct] = z;
    }
#pragma unroll
    for (int r = 0; r < 4; ++r) {
      float v0 = s[0][r] * scale, v1 = s[1][r] * scale;
      float v2 = s[2][r] * scale, v3 = s[3][r] * scale;
      float mx = fmaxf(fmaxf(v0, v1), fmaxf(v2, v3));
#pragma unroll
      for (int d2 = 1; d2 < 16; d2 <<= 1) mx = fmaxf(mx, __shfl_xor(mx, d2, 64));
      float mnew = fmaxf(mrow[r], mx);
      float corr = __expf(mrow[r] - mnew);
      mrow[r] = mnew;
      float p0 = __expf(v0 - mnew), p1 = __expf(v1 - mnew);
      float p2 = __expf(v2 - mnew), p3 = __expf(v3 - mnew);
      float rs = p0 + p1 + p2 + p3;
#pragma unroll
      for (int d2 = 1; d2 < 16; d2 <<= 1) rs += __shfl_xor(rs, d2, 64);
      lrow[r] = lrow[r] * corr + rs;
      oacc[0][r] *= corr;
      oacc[1][r] *= corr;
      const int prow = hi2 * 4 + r;
      lP[wv][prow * 64 + 0 * 16 + lo16] = p0;
      lP[wv][prow * 64 + 1 * 16 + lo16] = p1;
      lP[wv][prow * 64 + 2 * 16 + lo16] = p2;
      lP[wv][prow * 64 + 3 * 16 + lo16] = p3;
    }
    // intra-wave LDS write->read hazard: drain DS queue before cross-lane read
    asm volatile("s_waitcnt lgkmcnt(0)" ::: "memory");
#pragma unroll
    for (int c = 0; c < 2; ++c) {
      const float* pp = &lP[wv][lo16 * 64 + c * 32 + hi2 * 8];
      float4 pa = *(const float4*)pp;
      float4 pb = *(const float4*)(pp + 4);
      float pv[8] = {pa.x, pa.y, pa.z, pa.w, pb.x, pb.y, pb.z, pb.w};
      bf16x8 ph, pl;
#pragma unroll
      for (int j = 0; j < 8; ++j) {
        u16 hb = f2b(pv[j]);
        ph[j] = (short)hb;
        pl[j] = (short)f2b(pv[j] - b2f(hb));
      }
#pragma unroll
      for (int ct2 = 0; ct2 < 2; ++ct2) {
        bf16x8 vf0 = *(const bf16x8*)&lV[0][(ct2 * 16 + lo16) * 64 + c * 32 + hi2 * 8];
        bf16x8 vf1 = *(const bf16x8*)&lV[1][(ct2 * 16 + lo16) * 64 + c * 32 + hi2 * 8];
        oacc[ct2] = mfma_bf16(ph, vf0, oacc[ct2]);
        oacc[ct2] = mfma_bf16(ph, vf1, oacc[ct2]);
        oacc[ct2] = mfma_bf16(pl, vf0, oacc[ct2]);
      }
    }
  }
#pragma unroll
  for (int ct2 = 0; ct2 < 2; ++ct2)
#pragma unroll
    for (int r = 0; r < 4; ++r) {
      float v = oacc[ct2][r] / lrow[r];
      const int t = qt * 64 + wv * 16 + hi2 * 4 + r;
      const size_t idx = ((size_t)b * T_ + t) * D_ + h * 32 + ct2 * 16 + lo16;
      u16 hb = f2b(v);
      ohi[idx] = hb;
      olo[idx] = f2b(v - b2f(hb));
    }
}

// ---------------- fused residual add + LayerNorm ----------------
__global__ __launch_bounds__(256)
void k_lnadd(const float* hin, const float* __restrict__ add,
             const float* __restrict__ w, const float* __restrict__ b,
             float* hout, u16* __restrict__ hhi, u16* __restrict__ hlo) {
  const int row = blockIdx.x * 4 + (threadIdx.x >> 6);
  const int lane = threadIdx.x & 63;
  const size_t base = (size_t)row * D_ + lane * 2;
  float2 x = *(const float2*)(hin + base);
  float2 a = *(const float2*)(add + base);
  x.x += a.x; x.y += a.y;
  float s = x.x + x.y;
#pragma unroll
  for (int d2 = 1; d2 < 64; d2 <<= 1) s += __shfl_xor(s, d2, 64);
  const float m = s * (1.f / 128.f);
  float dx = x.x - m, dy = x.y - m;
  float q = dx * dx + dy * dy;
#pragma unroll
  for (int d2 = 1; d2 < 64; d2 <<= 1) q += __shfl_xor(q, d2, 64);
  const float inv = rsqrtf(q * (1.f / 128.f) + 1e-5f);
  const float2 ww = *(const float2*)(w + lane * 2);
  const float2 bb = *(const float2*)(b + lane * 2);
  float y0 = dx * inv * ww.x + bb.x;
  float y1 = dy * inv * ww.y + bb.y;
  float2 yo; yo.x = y0; yo.y = y1;
  *(float2*)(hout + base) = yo;
  u16 h0 = f2b(y0), h1 = f2b(y1);
  u16 l0 = f2b(y0 - b2f(h0)), l1 = f2b(y1 - b2f(h1));
  *(u32*)(hhi + base) = (u32)h0 | ((u32)h1 << 16);
  *(u32*)(hlo + base) = (u32)l0 | ((u32)l1 << 16);
}

// ---------------- head: final LN -> h out, cosine logits -> probs out + GRU gi precompute ----------------
__global__ __launch_bounds__(256)
void k_head(const float* __restrict__ hin, const float* __restrict__ w,
            const float* __restrict__ bws, const float* __restrict__ cn,
            const float* __restrict__ temp,
            const float* __restrict__ wih, const float* __restrict__ bih,
            float4* __restrict__ g4, float* __restrict__ out) {
  const int row = blockIdx.x * 4 + (threadIdx.x >> 6);
  const int lane = threadIdx.x & 63;
  const size_t base = (size_t)row * D_ + lane * 2;
  float2 x = *(const float2*)(hin + base);
  float s = x.x + x.y;
#pragma unroll
  for (int d2 = 1; d2 < 64; d2 <<= 1) s += __shfl_xor(s, d2, 64);
  float m = s * (1.f / 128.f);
  float dx = x.x - m, dy = x.y - m;
  float q = dx * dx + dy * dy;
#pragma unroll
  for (int d2 = 1; d2 < 64; d2 <<= 1) q += __shfl_xor(q, d2, 64);
  float inv = rsqrtf(q * (1.f / 128.f) + 1e-5f);
  float2 ww = *(const float2*)(w + lane * 2);
  float2 bb = *(const float2*)(bws + lane * 2);
  float y0 = dx * inv * ww.x + bb.x;
  float y1 = dy * inv * ww.y + bb.y;
  float2 yo; yo.x = y0; yo.y = y1;
  *(float2*)(out + OUT_H + base) = yo;
  float ss = y0 * y0 + y1 * y1;
#pragma unroll
  for (int d2 = 1; d2 < 64; d2 <<= 1) ss += __shfl_xor(ss, d2, 64);
  float nrm = fmaxf(sqrtf(ss), 1e-12f);
  float z0 = y0 / nrm, z1 = y1 / nrm;
  float lg[4];
#pragma unroll
  for (int rr = 0; rr < 4; ++rr)
    lg[rr] = z0 * cn[rr * 128 + lane * 2] + z1 * cn[rr * 128 + lane * 2 + 1];
#pragma unroll
  for (int d2 = 1; d2 < 64; d2 <<= 1) {
#pragma unroll
    for (int rr = 0; rr < 4; ++rr) lg[rr] += __shfl_xor(lg[rr], d2, 64);
  }
  float ts = 1.f / fmaxf(temp[0], 1e-4f);
#pragma unroll
  for (int rr = 0; rr < 4; ++rr) lg[rr] *= ts;
  float mx = fmaxf(fmaxf(lg[0], lg[1]), fmaxf(lg[2], lg[3]));
  float e0 = __expf(lg[0] - mx), e1 = __expf(lg[1] - mx);
  float e2 = __expf(lg[2] - mx), e3 = __expf(lg[3] - mx);
  float es = e0 + e1 + e2 + e3;
  float einv = 1.f / es;
  float p0 = e0 * einv, p1 = e1 * einv, p2 = e2 * einv, p3 = e3 * einv;
  if (lane < 4) {
    float pr = (lane == 0) ? p0 : (lane == 1) ? p1 : (lane == 2) ? p2 : p3;
    out[OUT_PROBS + (size_t)row * 4 + lane] = pr;
    // GRU input-gate preactivations, pre-scaled for exp2-based gates:
    //   x-slot: -log2e * gi_r ;  y-slot: -log2e * gi_z ;  z-slot: 2*log2e * gi_n
    float gi[3];
#pragma unroll
    for (int g = 0; g < 3; ++g) {
      const float* wr = wih + (g * 4 + lane) * 4;
      gi[g] = bih[g * 4 + lane] + wr[0] * p0 + wr[1] * p1 + wr[2] * p2 + wr[3] * p3;
    }
    const int b = row >> 10, t = row & 1023;
    float4 o4;
    o4.x = -LOG2E * gi[0];
    o4.y = -LOG2E * gi[1];
    o4.z = 2.f * LOG2E * gi[2];
    o4.w = pr;
    g4[(size_t)t * 64 + b * 4 + lane] = o4;
  }
}

// ---------------- GRU scan: producer wave (pure VALU+LDS) + consumer wave (global stores) ----------------
__global__ __launch_bounds__(128)
void k_scan(const float4* __restrict__ g4, const float* __restrict__ init,
            const float* __restrict__ whh, const float* __restrict__ bhh,
            float* __restrict__ out) {
  __shared__ float sbuf[2][64][64];
  const int tid = threadIdx.x;
  const int wave = tid >> 6;
  const int lane = tid & 63;

  if (wave == 0) {
    // ---- producer: sequential scan, stores ONLY to LDS (no vmcnt pollution) ----
    const int r = lane & 3;
    const float sc[3] = {-LOG2E, -LOG2E, 2.f * LOG2E};
    float Wh[3][4], Bh[3];
#pragma unroll
    for (int g = 0; g < 3; ++g) {
      Bh[g] = bhh[g * 4 + r] * sc[g];
#pragma unroll
      for (int j = 0; j < 4; ++j) Wh[g][j] = whh[(g * 4 + r) * 4 + j] * sc[g];
    }
    float st = init[lane];
    float4 pre[8];
#pragma unroll
    for (int d = 0; d < 8; ++d) pre[d] = g4[d * 64 + lane];

    for (int tc = 0; tc < 1024; tc += 8) {
      const int buf = (tc >> 6) & 1;
      const int sbase = tc & 63;
#pragma unroll
      for (int d = 0; d < 8; ++d) {
        float4 v = pre[d];
        const int tn = (tc + 8 + d < 1024) ? (tc + 8 + d) : 1023;  // branchless clamp
        pre[d] = g4[(size_t)tn * 64 + lane];                       // prefetch 8 steps ahead
        // quad state broadcast on the VALU pipe
        float s0 = qb0(st), s1 = qb1(st), s2 = qb2(st), s3 = qb3(st);
        float a_r = fmaf(Wh[0][3], s3, fmaf(Wh[0][2], s2, fmaf(Wh[0][1], s1, fmaf(Wh[0][0], s0, Bh[0] + v.x))));
        float a_z = fmaf(Wh[1][3], s3, fmaf(Wh[1][2], s2, fmaf(Wh[1][1], s1, fmaf(Wh[1][0], s0, Bh[1] + v.y))));
        float g_n = fmaf(Wh[2][3], s3, fmaf(Wh[2][2], s2, fmaf(Wh[2][1], s1, fmaf(Wh[2][0], s0, Bh[2]))));
        float rg = __builtin_amdgcn_rcpf(1.f + exp2f(a_r));   // sigmoid(gi_r+gh_r)
        float zg = __builtin_amdgcn_rcpf(1.f + exp2f(a_z));   // sigmoid(gi_z+gh_z)
        float nxp = fmaf(rg, g_n, v.z);                        // 2*log2e*(gi_n + r*gh_n)
        float ng = fmaf(-2.f, __builtin_amdgcn_rcpf(1.f + exp2f(nxp)), 1.f);  // tanh
        float sn = fmaf(zg, st - ng, ng);                      // (1-z)*n + z*s
        sn = fmaf(0.9f, sn, 0.1f * v.w);                       // temporal smoothing
        st = sn;
        sbuf[buf][sbase + d][lane] = sn;
      }
      if (((tc + 8) & 63) == 0) __syncthreads();   // 16 barriers, one per 64-step chunk
    }
    out[OUT_FS + lane] = st;
  } else {
    // ---- consumer: drain chunks to global (smoothed probs + fused argmax) ----
    for (int c = 0; c < 16; ++c) {
      __syncthreads();
      const float* src = &sbuf[c & 1][0][0];
#pragma unroll
      for (int i = 0; i < 16; ++i) {
        const int q = i * 64 + lane;
        const int s = q >> 4, b = q & 15;
        float4 v = *(const float4*)&src[s * 64 + b * 4];
        const int t = c * 64 + s;
        *(float4*)&out[OUT_SP + (size_t)b * 4096 + t * 4] = v;
        int am = 0; float bv = v.x;
        if (v.y > bv) { bv = v.y; am = 1; }
        if (v.z > bv) { bv = v.z; am = 2; }
        if (v.w > bv) { bv = v.w; am = 3; }
        out[OUT_REG + (size_t)b * 1024 + t] = (float)am;
      }
    }
  }
}

// ---------------- launch ----------------
extern "C" void kernel_launch(void* const* d_in, const int* in_sizes, int n_in,
                              void* d_out, int out_size, void* d_ws, size_t ws_size,
                              hipStream_t stream) {
  (void)in_sizes; (void)n_in; (void)out_size; (void)ws_size;
  const float* x     = (const float*)d_in[0];
  const float* init  = (const float*)d_in[1];
  const float* in_w  = (const float*)d_in[2];
  const float* in_b  = (const float*)d_in[3];
  const float* qkv_w = (const float*)d_in[4];
  const float* qkv_b = (const float*)d_in[5];
  const float* out_w = (const float*)d_in[6];
  const float* out_b = (const float*)d_in[7];
  const float* ln1w  = (const float*)d_in[8];
  const float* ln1b  = (const float*)d_in[9];
  const float* ff1w  = (const float*)d_in[10];
  const float* ff1b  = (const float*)d_in[11];
  const float* ff2w  = (const float*)d_in[12];
  const float* ff2b  = (const float*)d_in[13];
  const float* ln2w  = (const float*)d_in[14];
  const float* ln2b  = (const float*)d_in[15];
  const float* nw    = (const float*)d_in[16];
  const float* nb    = (const float*)d_in[17];
  const float* cent  = (const float*)d_in[18];
  const float* temp  = (const float*)d_in[19];
  const float* gwih  = (const float*)d_in[20];
  const float* gwhh  = (const float*)d_in[21];
  const float* gbih  = (const float*)d_in[22];
  const float* gbhh  = (const float*)d_in[23];
  float* out = (float*)d_out;

  char* wsp = (char*)d_ws;
  auto take = [&](size_t bytes) -> char* {
    char* p = wsp;
    wsp += (bytes + 255) & ~(size_t)255;
    return p;
  };
  u16* xhi = (u16*)take((size_t)1048576 * 2);
  u16* xlo = (u16*)take((size_t)1048576 * 2);
  float* hf = (float*)take((size_t)M_ * 128 * 4);
  u16* hhi = (u16*)take((size_t)M_ * 128 * 2);
  u16* hlo = (u16*)take((size_t)M_ * 128 * 2);
  char* U = take(33554432);                 // union: qkv planes / ff1 planes
  u16* qkvhi = (u16*)U;
  u16* qkvlo = (u16*)(U + 12582912);
  u16* f1hi = (u16*)U;
  u16* f1lo = (u16*)(U + 16777216);
  u16* vthi = (u16*)take((size_t)2097152 * 2);
  u16* vtlo = (u16*)take((size_t)2097152 * 2);
  u16* ohi = (u16*)take((size_t)2097152 * 2);
  u16* olo = (u16*)take((size_t)2097152 * 2);
  float* gtmp = (float*)take((size_t)M_ * 128 * 4);
  u16* inwhi = (u16*)take(8192 * 2);   u16* inwlo = (u16*)take(8192 * 2);
  u16* qwhi = (u16*)take(196608 * 2);  u16* qwlo = (u16*)take(196608 * 2);
  u16* owhi = (u16*)take(65536 * 2);   u16* owlo = (u16*)take(65536 * 2);
  u16* f1whi = (u16*)take(262144 * 2); u16* f1wlo = (u16*)take(262144 * 2);
  u16* f2whi = (u16*)take(262144 * 2); u16* f2wlo = (u16*)take(262144 * 2);
  float* cnorm = (float*)take(512 * 4);
  float4* g4 = (float4*)take((size_t)T_ * 64 * 16);   // {-L*gi_r, -L*gi_z, 2L*gi_n, p} per (t, b, r)

  k_split<<<4096, 256, 0, stream>>>(x, xhi, xlo, 1048576);
  k_split<<<32, 256, 0, stream>>>(in_w, inwhi, inwlo, 8192);
  k_split<<<768, 256, 0, stream>>>(qkv_w, qwhi, qwlo, 196608);
  k_split<<<256, 256, 0, stream>>>(out_w, owhi, owlo, 65536);
  k_split<<<1024, 256, 0, stream>>>(ff1w, f1whi, f1wlo, 262144);
  k_split<<<1024, 256, 0, stream>>>(ff2w, f2whi, f2wlo, 262144);
  k_cnorm<<<1, 64, 0, stream>>>(cent, cnorm);

  // input projection: h = x @ in_w^T + in_b
  k_gemm<0, 3><<<dim3(128, 2), 256, 0, stream>>>(xhi, xlo, inwhi, inwlo, in_b,
                                                 hf, hhi, hlo, 128, 64);

  for (int l = 0; l < 4; ++l) {
    k_gemm<0, 2><<<dim3(128, 6), 256, 0, stream>>>(
        hhi, hlo, qwhi + l * 49152, qwlo + l * 49152, qkv_b + l * 384,
        nullptr, qkvhi, qkvlo, 384, 128);
    k_vtprep<<<8192, 256, 0, stream>>>(qkvhi, qkvlo, vthi, vtlo);
    k_attn<<<dim3(16, 64), 256, 0, stream>>>(qkvhi, qkvlo, vthi, vtlo, ohi, olo);
    k_gemm<0, 1><<<dim3(128, 2), 256, 0, stream>>>(
        ohi, olo, owhi + l * 16384, owlo + l * 16384, out_b + l * 128,
        gtmp, nullptr, nullptr, 128, 128);
    k_lnadd<<<4096, 256, 0, stream>>>(hf, gtmp, ln1w + l * 128, ln1b + l * 128,
                                      hf, hhi, hlo);
    k_gemm<1, 2><<<dim3(128, 8), 256, 0, stream>>>(
        hhi, hlo, f1whi + l * 65536, f1wlo + l * 65536, ff1b + l * 512,
        nullptr, f1hi, f1lo, 512, 128);
    k_gemm<0, 1><<<dim3(128, 2), 256, 0, stream>>>(
        f1hi, f1lo, f2whi + l * 65536, f2wlo + l * 65536, ff2b + l * 128,
        gtmp, nullptr, nullptr, 128, 512);
    k_lnadd<<<4096, 256, 0, stream>>>(hf, gtmp, ln2w + l * 128, ln2b + l * 128,
                                      hf, hhi, hlo);
  }

  k_head<<<4096, 256, 0, stream>>>(hf, nw, nb, cnorm, temp, gwih, gbih, g4, out);
  k_scan<<<1, 128, 0, stream>>>(g4, init, gwhh, gbhh, out);
}